// Round 6
// baseline (116.852 us; speedup 1.0000x reference)
//
#include <hip/hip_runtime.h>
#include <math.h>

#define TPB 256
#define RBN 2016          // reducer blocks; +32 pair blocks = 2048 total (8/CU, all resident)
#define PBN 32            // pair blocks: 4 waves each, 1 i-row per wave -> 128 i's

__device__ __forceinline__ float waveReduceSum(float v) {
    #pragma unroll
    for (int off = 32; off > 0; off >>= 1)
        v += __shfl_down(v, off, 64);
    return v;
}

// ws layout: [0,RBN) partials sum(a-p)^2 ; [RBN,2RBN) partials sum(relu(P)^2) ;
//            [2RBN, 2RBN+PBN) partials parameter_penalty
__global__ __launch_bounds__(TPB, 8)
void fused_kernel(const float* __restrict__ a,
                  const float* __restrict__ p,
                  const float* __restrict__ Pm,
                  const float* __restrict__ S,
                  const int* __restrict__ ii,
                  const int* __restrict__ jj,
                  float* __restrict__ ws,
                  long nAP, long nP, int Npair, int D, int K)
{
    __shared__ float sm0[4], sm1[4];          // the ONLY LDS in this kernel (~32 B)
    const int wave = threadIdx.x >> 6;
    const int lane = threadIdx.x & 63;

    if ((int)blockIdx.x < PBN) {
        // ---------------- pair role: registers only ----------------
        const int iw = blockIdx.x * 4 + wave;      // wave's i index, 0..127
        float local = 0.f;

        if (iw < Npair && D == 1024) {
            const int ri = ii[iw];
            const float4* Si4 = (const float4*)(S + (long)ri * D);
            // full Si row across the wave: lane holds 4 float4 (16 floats)
            float4 x0 = Si4[lane];
            float4 x1 = Si4[lane + 64];
            float4 x2 = Si4[lane + 128];
            float4 x3 = Si4[lane + 192];
            const long riK = (long)ri * K;
            for (int j = 0; j < Npair; ++j) {
                const int rj = jj[j];
                const float4* Sj4 = (const float4*)(S + (long)rj * D);
                float4 y0 = Sj4[lane];
                float4 y1 = Sj4[lane + 64];
                float4 y2 = Sj4[lane + 128];
                float4 y3 = Sj4[lane + 192];
                float d2 = 0.f, e;
                e = x0.x - y0.x; d2 += e * e;
                e = x0.y - y0.y; d2 += e * e;
                e = x0.z - y0.z; d2 += e * e;
                e = x0.w - y0.w; d2 += e * e;
                e = x1.x - y1.x; d2 += e * e;
                e = x1.y - y1.y; d2 += e * e;
                e = x1.z - y1.z; d2 += e * e;
                e = x1.w - y1.w; d2 += e * e;
                e = x2.x - y2.x; d2 += e * e;
                e = x2.y - y2.y; d2 += e * e;
                e = x2.z - y2.z; d2 += e * e;
                e = x2.w - y2.w; d2 += e * e;
                e = x3.x - y3.x; d2 += e * e;
                e = x3.y - y3.y; d2 += e * e;
                e = x3.z - y3.z; d2 += e * e;
                e = x3.w - y3.w; d2 += e * e;
                d2 = waveReduceSum(d2);
                if (lane == 0 && d2 > 0.f)
                    local += fmaxf(Pm[riK + rj], 0.f) * sqrtf(d2);
            }
        } else if (iw < Npair) {
            // generic-D fallback (unused for this problem shape)
            const int ri = ii[iw];
            const float* Si = S + (long)ri * D;
            const long riK = (long)ri * K;
            for (int j = 0; j < Npair; ++j) {
                const int rj = jj[j];
                const float* Sj = S + (long)rj * D;
                float d2 = 0.f;
                for (int c = lane; c < D; c += 64) {
                    float e = Si[c] - Sj[c];
                    d2 += e * e;
                }
                d2 = waveReduceSum(d2);
                if (lane == 0 && d2 > 0.f)
                    local += fmaxf(Pm[riK + rj], 0.f) * sqrtf(d2);
            }
        }

        if (lane == 0) sm0[wave] = local;
        __syncthreads();
        if (threadIdx.x == 0)
            ws[2 * RBN + blockIdx.x] = sm0[0] + sm0[1] + sm0[2] + sm0[3];
    } else {
        // ---------------- reducer role (R2-proven 4-wide named batches) ----------------
        const int  rb     = blockIdx.x - PBN;
        const long gtid   = (long)rb * TPB + threadIdx.x;
        const long stride = (long)RBN * TPB;           // 516,096 threads

        const float4* a4 = (const float4*)a;
        const float4* p4 = (const float4*)p;
        const long n4  = nAP >> 2;                     // 4,194,304 -> 8 + tail
        const long nP4 = nP  >> 2;                     // 1,048,576 -> 2 + tail

        float s0a = 0.f, s0b = 0.f, s0c = 0.f, s0d = 0.f;
        long i = gtid;
        for (; i + 3 * stride < n4; i += 4 * stride) {
            float4 av0 = a4[i];
            float4 av1 = a4[i + stride];
            float4 av2 = a4[i + 2 * stride];
            float4 av3 = a4[i + 3 * stride];
            float4 pv0 = p4[i];
            float4 pv1 = p4[i + stride];
            float4 pv2 = p4[i + 2 * stride];
            float4 pv3 = p4[i + 3 * stride];
            float d;
            d = av0.x - pv0.x; s0a += d * d;
            d = av0.y - pv0.y; s0a += d * d;
            d = av0.z - pv0.z; s0a += d * d;
            d = av0.w - pv0.w; s0a += d * d;
            d = av1.x - pv1.x; s0b += d * d;
            d = av1.y - pv1.y; s0b += d * d;
            d = av1.z - pv1.z; s0b += d * d;
            d = av1.w - pv1.w; s0b += d * d;
            d = av2.x - pv2.x; s0c += d * d;
            d = av2.y - pv2.y; s0c += d * d;
            d = av2.z - pv2.z; s0c += d * d;
            d = av2.w - pv2.w; s0c += d * d;
            d = av3.x - pv3.x; s0d += d * d;
            d = av3.y - pv3.y; s0d += d * d;
            d = av3.z - pv3.z; s0d += d * d;
            d = av3.w - pv3.w; s0d += d * d;
        }
        for (; i < n4; i += stride) {                  // <=1 iter per thread
            float4 av = a4[i], pv = p4[i];
            float d;
            d = av.x - pv.x; s0a += d * d;
            d = av.y - pv.y; s0a += d * d;
            d = av.z - pv.z; s0a += d * d;
            d = av.w - pv.w; s0a += d * d;
        }

        float s1a = 0.f, s1b = 0.f;
        long q = gtid;
        for (; q + stride < nP4; q += 2 * stride) {
            float4 v0 = ((const float4*)Pm)[q];
            float4 v1 = ((const float4*)Pm)[q + stride];
            float r;
            r = fmaxf(v0.x, 0.f); s1a += r * r;
            r = fmaxf(v0.y, 0.f); s1a += r * r;
            r = fmaxf(v0.z, 0.f); s1a += r * r;
            r = fmaxf(v0.w, 0.f); s1a += r * r;
            r = fmaxf(v1.x, 0.f); s1b += r * r;
            r = fmaxf(v1.y, 0.f); s1b += r * r;
            r = fmaxf(v1.z, 0.f); s1b += r * r;
            r = fmaxf(v1.w, 0.f); s1b += r * r;
        }
        for (; q < nP4; q += stride) {                 // <=1 iter per thread
            float4 v = ((const float4*)Pm)[q];
            float r;
            r = fmaxf(v.x, 0.f); s1a += r * r;
            r = fmaxf(v.y, 0.f); s1a += r * r;
            r = fmaxf(v.z, 0.f); s1a += r * r;
            r = fmaxf(v.w, 0.f); s1a += r * r;
        }

        float s0 = waveReduceSum(s0a + s0b + s0c + s0d);
        float s1 = waveReduceSum(s1a + s1b);
        if (lane == 0) { sm0[wave] = s0; sm1[wave] = s1; }
        __syncthreads();
        if (threadIdx.x == 0) {
            ws[rb]       = sm0[0] + sm0[1] + sm0[2] + sm0[3];
            ws[RBN + rb] = sm1[0] + sm1[1] + sm1[2] + sm1[3];
        }
    }
}

__global__ void finalize_kernel(const float* __restrict__ ws,
                                const float* __restrict__ lamb,
                                float* __restrict__ out)
{
    float a0 = 0.f, a1 = 0.f, a2 = 0.f;
    const float4* w4 = (const float4*)ws;
    for (int i = threadIdx.x; i < RBN / 4; i += TPB) {   // RBN = 2016 = 504 float4
        float4 v = w4[i];
        a0 += v.x + v.y + v.z + v.w;
        float4 u = w4[RBN / 4 + i];
        a1 += u.x + u.y + u.z + u.w;
    }
    for (int i = threadIdx.x; i < PBN; i += TPB)
        a2 += ws[2 * RBN + i];

    a0 = waveReduceSum(a0);
    a1 = waveReduceSum(a1);
    a2 = waveReduceSum(a2);

    __shared__ float m0[4], m1[4], m2[4];
    int wave = threadIdx.x >> 6;
    int lane = threadIdx.x & 63;
    if (lane == 0) { m0[wave] = a0; m1[wave] = a1; m2[wave] = a2; }
    __syncthreads();
    if (threadIdx.x == 0) {
        float A0 = m0[0] + m0[1] + m0[2] + m0[3];
        float A1 = m1[0] + m1[1] + m1[2] + m1[3];
        float A2 = m2[0] + m2[1] + m2[2] + m2[3];
        out[0] = sqrtf(A0) + lamb[0] * (sqrtf(A1) + A2);
    }
}

extern "C" void kernel_launch(void* const* d_in, const int* in_sizes, int n_in,
                              void* d_out, int out_size, void* d_ws, size_t ws_size,
                              hipStream_t stream) {
    const float* actual = (const float*)d_in[0];
    const float* pred   = (const float*)d_in[1];
    const float* lamb   = (const float*)d_in[2];
    const float* Pm     = (const float*)d_in[3];
    const float* S      = (const float*)d_in[4];
    const int*   ii     = (const int*)d_in[5];
    const int*   jj     = (const int*)d_in[6];
    float* out = (float*)d_out;
    float* ws  = (float*)d_ws;

    long nAP   = in_sizes[0];                       // 4096*4096
    long nP    = in_sizes[3];                       // 2048*2048
    int  K     = (int)lround(sqrt((double)nP));     // 2048
    int  Npair = in_sizes[5];                       // 128
    int  D     = (int)(in_sizes[4] / K);            // 1024

    fused_kernel<<<PBN + RBN, TPB, 0, stream>>>(actual, pred, Pm, S, ii, jj, ws,
                                                nAP, nP, Npair, D, K);
    finalize_kernel<<<1, TPB, 0, stream>>>(ws, lamb, out);
}

// Round 7
// 97.304 us; speedup vs baseline: 1.2009x; 1.2009x over previous
//
#include <hip/hip_runtime.h>
#include <math.h>

#define TPB 256
#define RBN 1536          // reducer blocks
#define PBN 512           // pair blocks
#define NBLK (RBN + PBN)  // 2048 total = 8/CU, all resident

__device__ __forceinline__ float waveReduceSum(float v) {
    #pragma unroll
    for (int off = 32; off > 0; off >>= 1)
        v += __shfl_down(v, off, 64);
    return v;
}

// ws layout (floats): [0,RBN) s0 partials ; [RBN,2RBN) s1 partials ;
//                     [2RBN,2RBN+PBN) s2 partials ; ticket int at [2RBN+PBN]
__global__ __launch_bounds__(TPB, 8)
void fused_kernel(const float* __restrict__ a,
                  const float* __restrict__ p,
                  const float* __restrict__ Pm,
                  const float* __restrict__ S,
                  const int* __restrict__ ii,
                  const int* __restrict__ jj,
                  const float* __restrict__ lamb,
                  float* __restrict__ ws,
                  float* __restrict__ out,
                  long nAP, long nP, int Npair, int D, int K)
{
    __shared__ float sm0[4], sm1[4];
    __shared__ int   lastFlag;
    const int wave = threadIdx.x >> 6;
    const int lane = threadIdx.x & 63;
    int* ticket = (int*)(ws + 2 * RBN + PBN);

    if ((int)blockIdx.x < RBN) {
        // ---------------- reducer role (R2-proven 4-wide named batches) ----------------
        const int  rb     = blockIdx.x;
        const long gtid   = (long)rb * TPB + threadIdx.x;
        const long stride = (long)RBN * TPB;           // 393,216 threads

        const float4* a4 = (const float4*)a;
        const float4* p4 = (const float4*)p;
        const long n4  = nAP >> 2;                     // 4,194,304 -> ~10.7/thread
        const long nP4 = nP  >> 2;                     // 1,048,576 -> ~2.7/thread

        float s0a = 0.f, s0b = 0.f, s0c = 0.f, s0d = 0.f;
        long i = gtid;
        for (; i + 3 * stride < n4; i += 4 * stride) {
            float4 av0 = a4[i];
            float4 av1 = a4[i + stride];
            float4 av2 = a4[i + 2 * stride];
            float4 av3 = a4[i + 3 * stride];
            float4 pv0 = p4[i];
            float4 pv1 = p4[i + stride];
            float4 pv2 = p4[i + 2 * stride];
            float4 pv3 = p4[i + 3 * stride];
            float d;
            d = av0.x - pv0.x; s0a += d * d;
            d = av0.y - pv0.y; s0a += d * d;
            d = av0.z - pv0.z; s0a += d * d;
            d = av0.w - pv0.w; s0a += d * d;
            d = av1.x - pv1.x; s0b += d * d;
            d = av1.y - pv1.y; s0b += d * d;
            d = av1.z - pv1.z; s0b += d * d;
            d = av1.w - pv1.w; s0b += d * d;
            d = av2.x - pv2.x; s0c += d * d;
            d = av2.y - pv2.y; s0c += d * d;
            d = av2.z - pv2.z; s0c += d * d;
            d = av2.w - pv2.w; s0c += d * d;
            d = av3.x - pv3.x; s0d += d * d;
            d = av3.y - pv3.y; s0d += d * d;
            d = av3.z - pv3.z; s0d += d * d;
            d = av3.w - pv3.w; s0d += d * d;
        }
        for (; i < n4; i += stride) {                  // 2-3 iters per thread
            float4 av = a4[i], pv = p4[i];
            float d;
            d = av.x - pv.x; s0a += d * d;
            d = av.y - pv.y; s0a += d * d;
            d = av.z - pv.z; s0a += d * d;
            d = av.w - pv.w; s0a += d * d;
        }

        float s1a = 0.f, s1b = 0.f;
        long q = gtid;
        for (; q + stride < nP4; q += 2 * stride) {
            float4 v0 = ((const float4*)Pm)[q];
            float4 v1 = ((const float4*)Pm)[q + stride];
            float r;
            r = fmaxf(v0.x, 0.f); s1a += r * r;
            r = fmaxf(v0.y, 0.f); s1a += r * r;
            r = fmaxf(v0.z, 0.f); s1a += r * r;
            r = fmaxf(v0.w, 0.f); s1a += r * r;
            r = fmaxf(v1.x, 0.f); s1b += r * r;
            r = fmaxf(v1.y, 0.f); s1b += r * r;
            r = fmaxf(v1.z, 0.f); s1b += r * r;
            r = fmaxf(v1.w, 0.f); s1b += r * r;
        }
        for (; q < nP4; q += stride) {
            float4 v = ((const float4*)Pm)[q];
            float r;
            r = fmaxf(v.x, 0.f); s1a += r * r;
            r = fmaxf(v.y, 0.f); s1a += r * r;
            r = fmaxf(v.z, 0.f); s1a += r * r;
            r = fmaxf(v.w, 0.f); s1a += r * r;
        }

        float s0 = waveReduceSum(s0a + s0b + s0c + s0d);
        float s1 = waveReduceSum(s1a + s1b);
        if (lane == 0) { sm0[wave] = s0; sm1[wave] = s1; }
        __syncthreads();
        if (threadIdx.x == 0) {
            ws[rb]       = sm0[0] + sm0[1] + sm0[2] + sm0[3];
            ws[RBN + rb] = sm1[0] + sm1[1] + sm1[2] + sm1[3];
        }
    } else {
        // ---------------- pair role: wide (2048 waves), Si in registers ----------------
        const int pb = blockIdx.x - RBN;               // 0..PBN-1
        const int gw = pb * 4 + wave;                  // 0..2047
        const long totalPairs = (long)Npair * Npair;
        const long ppw = (totalPairs + 4L * PBN - 1) / (4L * PBN);   // 8 for Npair=128
        const long p0 = (long)gw * ppw;
        const long p1 = (p0 + ppw < totalPairs) ? (p0 + ppw) : totalPairs;

        float local = 0.f;
        if (D == 1024) {
            int curI = -1, ri = 0;
            float4 x0, x1, x2, x3;
            for (long pr = p0; pr < p1; ++pr) {
                int i = (int)(pr / Npair);
                int j = (int)(pr - (long)i * Npair);
                if (i != curI) {
                    ri = ii[i];
                    const float4* Si4 = (const float4*)(S + (long)ri * D);
                    x0 = Si4[lane];
                    x1 = Si4[lane + 64];
                    x2 = Si4[lane + 128];
                    x3 = Si4[lane + 192];
                    curI = i;
                }
                const int rj = jj[j];
                const float4* Sj4 = (const float4*)(S + (long)rj * D);
                float4 y0 = Sj4[lane];
                float4 y1 = Sj4[lane + 64];
                float4 y2 = Sj4[lane + 128];
                float4 y3 = Sj4[lane + 192];
                float d2 = 0.f, e;
                e = x0.x - y0.x; d2 += e * e;
                e = x0.y - y0.y; d2 += e * e;
                e = x0.z - y0.z; d2 += e * e;
                e = x0.w - y0.w; d2 += e * e;
                e = x1.x - y1.x; d2 += e * e;
                e = x1.y - y1.y; d2 += e * e;
                e = x1.z - y1.z; d2 += e * e;
                e = x1.w - y1.w; d2 += e * e;
                e = x2.x - y2.x; d2 += e * e;
                e = x2.y - y2.y; d2 += e * e;
                e = x2.z - y2.z; d2 += e * e;
                e = x2.w - y2.w; d2 += e * e;
                e = x3.x - y3.x; d2 += e * e;
                e = x3.y - y3.y; d2 += e * e;
                e = x3.z - y3.z; d2 += e * e;
                e = x3.w - y3.w; d2 += e * e;
                d2 = waveReduceSum(d2);
                if (lane == 0 && d2 > 0.f)
                    local += fmaxf(Pm[(long)ri * K + rj], 0.f) * sqrtf(d2);
            }
        } else {
            for (long pr = p0; pr < p1; ++pr) {
                int i = (int)(pr / Npair);
                int j = (int)(pr - (long)i * Npair);
                const int ri = ii[i];
                const int rj = jj[j];
                const float* Si = S + (long)ri * D;
                const float* Sj = S + (long)rj * D;
                float d2 = 0.f;
                for (int c = lane; c < D; c += 64) {
                    float e = Si[c] - Sj[c];
                    d2 += e * e;
                }
                d2 = waveReduceSum(d2);
                if (lane == 0 && d2 > 0.f)
                    local += fmaxf(Pm[(long)ri * K + rj], 0.f) * sqrtf(d2);
            }
        }
        if (lane == 0) sm0[wave] = local;
        __syncthreads();
        if (threadIdx.x == 0)
            ws[2 * RBN + pb] = sm0[0] + sm0[1] + sm0[2] + sm0[3];
    }

    // ---------------- last-block finalize (deterministic: fixed-order reduce) -------
    __syncthreads();
    if (threadIdx.x == 0) {
        __threadfence();
        int old = atomicAdd(ticket, 1);
        lastFlag = (old == NBLK - 1);
    }
    __syncthreads();
    if (lastFlag) {
        __threadfence();
        float a0 = 0.f, a1 = 0.f, a2 = 0.f;
        for (int t = threadIdx.x; t < RBN; t += TPB) {
            a0 += ws[t];
            a1 += ws[RBN + t];
        }
        for (int t = threadIdx.x; t < PBN; t += TPB)
            a2 += ws[2 * RBN + t];

        a0 = waveReduceSum(a0);
        a1 = waveReduceSum(a1);
        a2 = waveReduceSum(a2);

        __shared__ float m0[4], m1[4], m2[4];
        if (lane == 0) { m0[wave] = a0; m1[wave] = a1; m2[wave] = a2; }
        __syncthreads();
        if (threadIdx.x == 0) {
            float A0 = m0[0] + m0[1] + m0[2] + m0[3];
            float A1 = m1[0] + m1[1] + m1[2] + m1[3];
            float A2 = m2[0] + m2[1] + m2[2] + m2[3];
            out[0] = sqrtf(A0) + lamb[0] * (sqrtf(A1) + A2);
        }
    }
}

extern "C" void kernel_launch(void* const* d_in, const int* in_sizes, int n_in,
                              void* d_out, int out_size, void* d_ws, size_t ws_size,
                              hipStream_t stream) {
    const float* actual = (const float*)d_in[0];
    const float* pred   = (const float*)d_in[1];
    const float* lamb   = (const float*)d_in[2];
    const float* Pm     = (const float*)d_in[3];
    const float* S      = (const float*)d_in[4];
    const int*   ii     = (const int*)d_in[5];
    const int*   jj     = (const int*)d_in[6];
    float* out = (float*)d_out;
    float* ws  = (float*)d_ws;

    long nAP   = in_sizes[0];                       // 4096*4096
    long nP    = in_sizes[3];                       // 2048*2048
    int  K     = (int)lround(sqrt((double)nP));     // 2048
    int  Npair = in_sizes[5];                       // 128
    int  D     = (int)(in_sizes[4] / K);            // 1024

    // zero the ticket counter (int at float offset 2*RBN+PBN)
    hipMemsetAsync(ws + 2 * RBN + PBN, 0, sizeof(int), stream);

    fused_kernel<<<NBLK, TPB, 0, stream>>>(actual, pred, Pm, S, ii, jj, lamb,
                                           ws, out, nAP, nP, Npair, D, K);
}

// Round 8
// 35.728 us; speedup vs baseline: 3.2706x; 2.7235x over previous
//
#include <hip/hip_runtime.h>
#include <math.h>

#define BR 1024   // reducer blocks
#define BP 1024   // pair blocks
#define TPB 256

__device__ __forceinline__ float waveReduceSum(float v) {
    #pragma unroll
    for (int off = 32; off > 0; off >>= 1)
        v += __shfl_down(v, off, 64);
    return v;
}

// Fused kernel.
// blocks [0, BP):      parameter_penalty pairs -> ws[2*BR + b]
// blocks [BP, BP+BR):  sum((a-p)^2) -> ws[rb], sum(relu(P)^2) -> ws[BR + rb]
__global__ __launch_bounds__(256, 8)
void fused_kernel(const float* __restrict__ a,
                  const float* __restrict__ p,
                  const float* __restrict__ Pm,
                  const float* __restrict__ S,
                  const int* __restrict__ ii,
                  const int* __restrict__ jj,
                  float* __restrict__ ws,
                  long nAP, long nP, int Npair, int D, int K)
{
    __shared__ float sm0[4], sm1[4];
    const int wave = threadIdx.x >> 6;
    const int lane = threadIdx.x & 63;
    const int bid  = blockIdx.x;

    if (bid < BP) {
        // ---- pair role: 16 pairs per block, 4 per wave (R2 mapping) ----
        // Single delta vs R2: Si is loaded ONCE per wave into registers
        // (i is constant across the wave's 4 pairs when 4 | Npair), and the
        // 4 wave-reductions are deferred so their shfl chains pipeline.
        const int totalPairs = Npair * Npair;
        const int base = bid * 16 + wave * 4;
        float local = 0.f;

        if (base < totalPairs && D == 1024 && (base % Npair) + 3 < Npair) {
            const int i  = base / Npair;
            const int j0 = base - i * Npair;
            const int ri = ii[i];
            const float4* Si4 = (const float4*)(S + (long)ri * D);
            float4 x0 = Si4[lane];
            float4 x1 = Si4[lane + 64];
            float4 x2 = Si4[lane + 128];
            float4 x3 = Si4[lane + 192];
            const long riK = (long)ri * K;

            float d2q[4];
            int   rjq[4];
            #pragma unroll
            for (int q = 0; q < 4; ++q) {
                const int rj = jj[j0 + q];
                rjq[q] = rj;
                const float4* Sj4 = (const float4*)(S + (long)rj * D);
                float4 y0 = Sj4[lane];
                float4 y1 = Sj4[lane + 64];
                float4 y2 = Sj4[lane + 128];
                float4 y3 = Sj4[lane + 192];
                float d2 = 0.f, e;
                e = x0.x - y0.x; d2 += e * e;
                e = x0.y - y0.y; d2 += e * e;
                e = x0.z - y0.z; d2 += e * e;
                e = x0.w - y0.w; d2 += e * e;
                e = x1.x - y1.x; d2 += e * e;
                e = x1.y - y1.y; d2 += e * e;
                e = x1.z - y1.z; d2 += e * e;
                e = x1.w - y1.w; d2 += e * e;
                e = x2.x - y2.x; d2 += e * e;
                e = x2.y - y2.y; d2 += e * e;
                e = x2.z - y2.z; d2 += e * e;
                e = x2.w - y2.w; d2 += e * e;
                e = x3.x - y3.x; d2 += e * e;
                e = x3.y - y3.y; d2 += e * e;
                e = x3.z - y3.z; d2 += e * e;
                e = x3.w - y3.w; d2 += e * e;
                d2q[q] = d2;
            }
            #pragma unroll
            for (int q = 0; q < 4; ++q)
                d2q[q] = waveReduceSum(d2q[q]);
            if (lane == 0) {
                #pragma unroll
                for (int q = 0; q < 4; ++q)
                    if (d2q[q] > 0.f)
                        local += fmaxf(Pm[riK + rjq[q]], 0.f) * sqrtf(d2q[q]);
            }
        } else {
            // generic fallback (R2 original per-pair path)
            #pragma unroll
            for (int q = 0; q < 4; ++q) {
                int pair = base + q;
                if (pair < totalPairs) {
                    int i = pair / Npair;
                    int j = pair - i * Npair;
                    int ri = ii[i];
                    int rj = jj[j];
                    const float* Si = S + (long)ri * D;
                    const float* Sj = S + (long)rj * D;
                    float d2 = 0.f;
                    for (int c = lane; c < D; c += 64) {
                        float e = Si[c] - Sj[c];
                        d2 += e * e;
                    }
                    d2 = waveReduceSum(d2);
                    if (lane == 0 && d2 > 0.f)
                        local += fmaxf(Pm[(long)ri * K + rj], 0.f) * sqrtf(d2);
                }
            }
        }
        if (lane == 0) sm0[wave] = local;
        __syncthreads();
        if (threadIdx.x == 0)
            ws[2 * BR + bid] = sm0[0] + sm0[1] + sm0[2] + sm0[3];
    } else {
        // ---- reducer role (VERBATIM R2) ----
        const int rb = bid - BP;
        const long tid    = (long)rb * TPB + threadIdx.x;
        const long stride = (long)BR * TPB;

        const float4* a4 = (const float4*)a;
        const float4* p4 = (const float4*)p;
        long n4 = nAP >> 2;

        float s0a = 0.f, s0b = 0.f, s0c = 0.f, s0d = 0.f;
        long i = tid;
        for (; i + 3 * stride < n4; i += 4 * stride) {
            float4 av0 = a4[i];
            float4 av1 = a4[i + stride];
            float4 av2 = a4[i + 2 * stride];
            float4 av3 = a4[i + 3 * stride];
            float4 pv0 = p4[i];
            float4 pv1 = p4[i + stride];
            float4 pv2 = p4[i + 2 * stride];
            float4 pv3 = p4[i + 3 * stride];
            float d;
            d = av0.x - pv0.x; s0a += d * d;
            d = av0.y - pv0.y; s0a += d * d;
            d = av0.z - pv0.z; s0a += d * d;
            d = av0.w - pv0.w; s0a += d * d;
            d = av1.x - pv1.x; s0b += d * d;
            d = av1.y - pv1.y; s0b += d * d;
            d = av1.z - pv1.z; s0b += d * d;
            d = av1.w - pv1.w; s0b += d * d;
            d = av2.x - pv2.x; s0c += d * d;
            d = av2.y - pv2.y; s0c += d * d;
            d = av2.z - pv2.z; s0c += d * d;
            d = av2.w - pv2.w; s0c += d * d;
            d = av3.x - pv3.x; s0d += d * d;
            d = av3.y - pv3.y; s0d += d * d;
            d = av3.z - pv3.z; s0d += d * d;
            d = av3.w - pv3.w; s0d += d * d;
        }
        for (; i < n4; i += stride) {
            float4 av = a4[i], pv = p4[i];
            float d;
            d = av.x - pv.x; s0a += d * d;
            d = av.y - pv.y; s0a += d * d;
            d = av.z - pv.z; s0a += d * d;
            d = av.w - pv.w; s0a += d * d;
        }

        const float4* P4 = (const float4*)Pm;
        long nP4 = nP >> 2;
        float s1a = 0.f, s1b = 0.f;
        i = tid;
        for (; i + stride < nP4; i += 2 * stride) {
            float4 v0 = P4[i];
            float4 v1 = P4[i + stride];
            float r;
            r = fmaxf(v0.x, 0.f); s1a += r * r;
            r = fmaxf(v0.y, 0.f); s1a += r * r;
            r = fmaxf(v0.z, 0.f); s1a += r * r;
            r = fmaxf(v0.w, 0.f); s1a += r * r;
            r = fmaxf(v1.x, 0.f); s1b += r * r;
            r = fmaxf(v1.y, 0.f); s1b += r * r;
            r = fmaxf(v1.z, 0.f); s1b += r * r;
            r = fmaxf(v1.w, 0.f); s1b += r * r;
        }
        for (; i < nP4; i += stride) {
            float4 v = P4[i];
            float r;
            r = fmaxf(v.x, 0.f); s1a += r * r;
            r = fmaxf(v.y, 0.f); s1a += r * r;
            r = fmaxf(v.z, 0.f); s1a += r * r;
            r = fmaxf(v.w, 0.f); s1a += r * r;
        }

        float s0 = waveReduceSum(s0a + s0b + s0c + s0d);
        float s1 = waveReduceSum(s1a + s1b);
        if (lane == 0) { sm0[wave] = s0; sm1[wave] = s1; }
        __syncthreads();
        if (threadIdx.x == 0) {
            ws[rb]      = sm0[0] + sm0[1] + sm0[2] + sm0[3];
            ws[BR + rb] = sm1[0] + sm1[1] + sm1[2] + sm1[3];
        }
    }
}

__global__ void finalize_kernel(const float* __restrict__ ws,
                                const float* __restrict__ lamb,
                                float* __restrict__ out)
{
    float a0 = 0.f, a1 = 0.f, a2 = 0.f;
    for (int i = threadIdx.x; i < BR; i += TPB) {
        a0 += ws[i];
        a1 += ws[BR + i];
    }
    for (int i = threadIdx.x; i < BP; i += TPB)
        a2 += ws[2 * BR + i];

    a0 = waveReduceSum(a0);
    a1 = waveReduceSum(a1);
    a2 = waveReduceSum(a2);

    __shared__ float m0[4], m1[4], m2[4];
    int wave = threadIdx.x >> 6;
    int lane = threadIdx.x & 63;
    if (lane == 0) { m0[wave] = a0; m1[wave] = a1; m2[wave] = a2; }
    __syncthreads();
    if (threadIdx.x == 0) {
        float A0 = m0[0] + m0[1] + m0[2] + m0[3];
        float A1 = m1[0] + m1[1] + m1[2] + m1[3];
        float A2 = m2[0] + m2[1] + m2[2] + m2[3];
        out[0] = sqrtf(A0) + lamb[0] * (sqrtf(A1) + A2);
    }
}

extern "C" void kernel_launch(void* const* d_in, const int* in_sizes, int n_in,
                              void* d_out, int out_size, void* d_ws, size_t ws_size,
                              hipStream_t stream) {
    const float* actual = (const float*)d_in[0];
    const float* pred   = (const float*)d_in[1];
    const float* lamb   = (const float*)d_in[2];
    const float* Pm     = (const float*)d_in[3];
    const float* S      = (const float*)d_in[4];
    const int*   ii     = (const int*)d_in[5];
    const int*   jj     = (const int*)d_in[6];
    float* out = (float*)d_out;
    float* ws  = (float*)d_ws;

    long nAP   = in_sizes[0];                       // 4096*4096
    long nP    = in_sizes[3];                       // 2048*2048
    int  K     = (int)lround(sqrt((double)nP));     // 2048
    int  Npair = in_sizes[5];                       // 128
    int  D     = (int)(in_sizes[4] / K);            // 1024

    fused_kernel<<<BP + BR, TPB, 0, stream>>>(actual, pred, Pm, S, ii, jj, ws,
                                              nAP, nP, Npair, D, K);
    finalize_kernel<<<1, TPB, 0, stream>>>(ws, lamb, out);
}